// Round 2
// baseline (15959.084 us; speedup 1.0000x reference)
//
#include <hip/hip_runtime.h>
#include <stdint.h>

typedef unsigned short ushort_t;
typedef unsigned int uint32;

#define SEQ   2048
#define BATCH 64
#define INDIM 128
#define HID   256
#define NP    1024      // 4*H packed gate columns, p = n*4 + g
#define KTOT  384       // H (recurrent) + I (input)
#define NWG   64
#define NCOL  16        // packed columns per WG (4 hidden cols x 4 gates)
#define HSZ   (BATCH*SEQ*HID)

typedef __attribute__((ext_vector_type(8))) short short8;
typedef __attribute__((ext_vector_type(4))) float float4_t;

__device__ __forceinline__ ushort_t f2bf(float f) {
  uint32 u = __builtin_bit_cast(uint32, f);
  u += 0x7FFFu + ((u >> 16) & 1u);           // round-to-nearest-even
  return (ushort_t)(u >> 16);
}
__device__ __forceinline__ float fast_sigmoid(float x) {
  return 1.0f / (1.0f + __expf(-x));
}
__device__ __forceinline__ float fast_tanh(float x) {
  return 1.0f - 2.0f / (__expf(2.0f * x) + 1.0f);
}
template<int CTRL>
__device__ __forceinline__ float bcast_quad(float v) {
  int r = __builtin_amdgcn_mov_dpp(__builtin_bit_cast(int, v), CTRL, 0xF, 0xF, true);
  return __builtin_bit_cast(float, r);
}

// ---------------------------------------------------------------------------
// Pack kernel: build BM[k][p] (bf16, k<256 -> W rows, k>=256 -> U rows),
// packed bias bp[p], zero h double-buffer slot 0 and barrier flags.
// Packing: p = n*4 + g  (g: 0=f,1=i,2=o,3=c~)
// ---------------------------------------------------------------------------
__global__ void pack_init(const float* __restrict__ Wf, const float* __restrict__ Wi,
                          const float* __restrict__ Wo, const float* __restrict__ Wc,
                          const float* __restrict__ Uf, const float* __restrict__ Ui,
                          const float* __restrict__ Uo, const float* __restrict__ Uc,
                          const float* __restrict__ bf_, const float* __restrict__ bi_,
                          const float* __restrict__ bo_, const float* __restrict__ bc_,
                          ushort_t* __restrict__ BM, float* __restrict__ bp,
                          ushort_t* __restrict__ hbuf, uint32* __restrict__ flags) {
  int idx = blockIdx.x * 256 + threadIdx.x;
  if (idx < KTOT * NP) {
    int k = idx >> 10;
    int p = idx & (NP - 1);
    int g = p & 3, n = p >> 2;
    const float* W4[4] = {Wf, Wi, Wo, Wc};
    const float* U4[4] = {Uf, Ui, Uo, Uc};
    float v = (k < HID) ? W4[g][k * HID + n] : U4[g][(k - HID) * HID + n];
    BM[idx] = f2bf(v);
  }
  if (idx < NP) {
    int g = idx & 3, n = idx >> 2;
    const float* B4[4] = {bf_, bi_, bo_, bc_};
    bp[idx] = B4[g][n];
  }
  if (idx < BATCH * HID) hbuf[idx] = 0;   // h buffer 0 (t=0 reads zeros)
  if (idx < NWG) flags[idx] = 0;
}

// ---------------------------------------------------------------------------
// Persistent recurrence kernel. Grid = 64 WGs x 256 threads (4 waves).
// WG j owns packed cols [j*16, j*16+16). Wave w owns batch rows [w*16,w*16+16).
// Weight slice (384x16 bf16) held in VGPRs as MFMA B-fragments for all 2048
// steps. One flag-array grid barrier per step; h double-buffered in ws.
// MFMA 16x16x32 bf16 layouts:
//   A[m][k]: m = lane&15, k = (lane>>4)*8 + j
//   B[k][n]: n = lane&15, k = (lane>>4)*8 + j
//   C[row][col]: col = lane&15, row = (lane>>4)*4 + r     (HW-verified, m89)
// ---------------------------------------------------------------------------
__global__ __launch_bounds__(256, 1) void lstm_seq(
    const float* __restrict__ x, const ushort_t* __restrict__ BM,
    const float* __restrict__ bp, ushort_t* hbuf, uint32* flags,
    float* __restrict__ out)
{
  const int j    = blockIdx.x;
  const int tid  = threadIdx.x;
  const int wave = tid >> 6;
  const int lane = tid & 63;
  const int lhi  = lane >> 4;    // 0..3
  const int llo  = lane & 15;    // 0..15

  // --- load persistent B fragments (one-time, column gather) ---
  short8 bfrag[12];
#pragma unroll
  for (int kf = 0; kf < 12; ++kf) {
#pragma unroll
    for (int e = 0; e < 8; ++e) {
      int k = kf * 32 + lhi * 8 + e;
      bfrag[kf][e] = (short)BM[k * NP + j * NCOL + llo];
    }
  }
  const float bias = bp[j * NCOL + llo];

  float c_reg[4] = {0.f, 0.f, 0.f, 0.f};
  const int arow  = wave * 16 + llo;        // batch row this lane LOADS (A layout)
  const int crow0 = wave * 16 + lhi * 4;    // batch row base this lane OWNS (C layout)
  const int nn    = llo >> 2;               // local hidden col 0..3
  const int nglob = j * 4 + nn;             // global hidden col
  const int g     = lane & 3;               // gate id of this lane's column

  ushort_t* hb0 = hbuf;
  ushort_t* hb1 = hbuf + BATCH * HID;

  for (int t = 0; t < SEQ; ++t) {
    const ushort_t* hbr = (t & 1) ? hb1 : hb0;   // read h_{t}
    ushort_t*       hbw = (t & 1) ? hb0 : hb1;   // write h_{t+1}

    // --- A fragments: recurrent part (bf16 from h buffer) ---
    short8 af[12];
    const ushort_t* hrow = hbr + arow * HID + lhi * 8;
#pragma unroll
    for (int kf = 0; kf < 8; ++kf)
      af[kf] = *(const short8*)(hrow + kf * 32);
    // --- A fragments: input part (fp32 x -> bf16) ---
    const float* xrow = x + (arow * SEQ + t) * INDIM + lhi * 8;
#pragma unroll
    for (int q = 0; q < 4; ++q) {
      float4_t xa = *(const float4_t*)(xrow + q * 32);
      float4_t xb = *(const float4_t*)(xrow + q * 32 + 4);
      short8 s;
      s[0] = (short)f2bf(xa[0]); s[1] = (short)f2bf(xa[1]);
      s[2] = (short)f2bf(xa[2]); s[3] = (short)f2bf(xa[3]);
      s[4] = (short)f2bf(xb[0]); s[5] = (short)f2bf(xb[1]);
      s[6] = (short)f2bf(xb[2]); s[7] = (short)f2bf(xb[3]);
      af[8 + q] = s;
    }

    // --- GEMM: g = b + [h | x_t] @ [W; U]  (fp32 accum) ---
    float4_t acc = {bias, bias, bias, bias};
#pragma unroll
    for (int kf = 0; kf < 12; ++kf)
      acc = __builtin_amdgcn_mfma_f32_16x16x32_bf16(af[kf], bfrag[kf], acc, 0, 0, 0);

    // --- gates + state update. All four activations are SIGMOID (per ref). ---
#pragma unroll
    for (int r = 0; r < 4; ++r) {
      float s  = fast_sigmoid(acc[r]);
      float fv = bcast_quad<0x00>(s);   // gate f  (lane g=0 of quad)
      float iv = bcast_quad<0x55>(s);   // gate i
      float ov = bcast_quad<0xAA>(s);   // gate o
      float cv = bcast_quad<0xFF>(s);   // gate c~
      float cn = fv * c_reg[r] + iv * cv;
      c_reg[r] = cn;
      float hv = ov * fast_tanh(cn);
      if (g == 0) {
        int row = crow0 + r;
        hbw[row * HID + nglob] = f2bf(hv);
        out[(row * SEQ + t) * HID + nglob] = hv;
        if (t == SEQ - 1) {
          out[HSZ + row * HID + nglob] = hv;                 // h_T
          out[HSZ + BATCH * HID + row * HID + nglob] = cn;   // c_T
        }
      }
    }

    // --- grid barrier (skip after last step) ---
    if (t < SEQ - 1) {
      __syncthreads();   // drains vmcnt per wave before s_barrier
      if (tid == 0) {
        __builtin_amdgcn_fence(__ATOMIC_RELEASE, "agent");
        __hip_atomic_store(&flags[j], (uint32)(t + 1), __ATOMIC_RELAXED,
                           __HIP_MEMORY_SCOPE_AGENT);
      }
      if (tid < NWG) {
        while (__hip_atomic_load(&flags[tid], __ATOMIC_RELAXED,
                                 __HIP_MEMORY_SCOPE_AGENT) <= (uint32)t) {
          __builtin_amdgcn_s_sleep(1);
        }
      }
      __syncthreads();
      __builtin_amdgcn_fence(__ATOMIC_ACQUIRE, "agent");
    }
  }
}

// ---------------------------------------------------------------------------
// Workspace layout (bytes):
//   [0, 786432)        BM    bf16 384x1024
//   [786432, 790528)   bp    fp32 1024
//   [790528, 856064)   hbuf  bf16 2 x 64 x 256 (double buffer)
//   [856064, 856320)   flags uint32 x 64
// Total < 1 MB.
// ---------------------------------------------------------------------------
extern "C" void kernel_launch(void* const* d_in, const int* in_sizes, int n_in,
                              void* d_out, int out_size, void* d_ws, size_t ws_size,
                              hipStream_t stream) {
  const float* xp  = (const float*)d_in[0];
  const float* Uf  = (const float*)d_in[1];
  const float* Wf  = (const float*)d_in[2];
  const float* bf_ = (const float*)d_in[3];
  const float* Ui  = (const float*)d_in[4];
  const float* Wi  = (const float*)d_in[5];
  const float* bi_ = (const float*)d_in[6];
  const float* Uo  = (const float*)d_in[7];
  const float* Wo  = (const float*)d_in[8];
  const float* bo_ = (const float*)d_in[9];
  const float* Uc  = (const float*)d_in[10];
  const float* Wc  = (const float*)d_in[11];
  const float* bc_ = (const float*)d_in[12];

  char* ws = (char*)d_ws;
  ushort_t* BM    = (ushort_t*)(ws);
  float*    bp    = (float*)(ws + 786432);
  ushort_t* hbuf  = (ushort_t*)(ws + 790528);
  uint32*   flags = (uint32*)(ws + 856064);
  float*    out   = (float*)d_out;

  pack_init<<<1536, 256, 0, stream>>>(Wf, Wi, Wo, Wc, Uf, Ui, Uo, Uc,
                                      bf_, bi_, bo_, bc_, BM, bp, hbuf, flags);
  lstm_seq<<<NWG, 256, 0, stream>>>(xp, BM, bp, hbuf, flags, out);
}

// Round 3
// 6891.838 us; speedup vs baseline: 2.3156x; 2.3156x over previous
//
#include <hip/hip_runtime.h>
#include <stdint.h>

typedef unsigned short ushort_t;
typedef unsigned int uint32;

#define SEQ   2048
#define BATCH 64
#define INDIM 128
#define HID   256
#define NP    1024      // 4*H packed gate columns, p = n*4 + g
#define KTOT  384       // H (recurrent) + I (input)
#define NWG   64
#define NCOL  16        // packed columns per WG (4 hidden cols x 4 gates)
#define HSZ   (BATCH*SEQ*HID)

typedef __attribute__((ext_vector_type(8))) short short8;
typedef __attribute__((ext_vector_type(4))) float float4_t;

__device__ __forceinline__ ushort_t f2bf(float f) {
  uint32 u = __builtin_bit_cast(uint32, f);
  u += 0x7FFFu + ((u >> 16) & 1u);           // round-to-nearest-even
  return (ushort_t)(u >> 16);
}
__device__ __forceinline__ float fast_sigmoid(float x) {
  return 1.0f / (1.0f + __expf(-x));
}
__device__ __forceinline__ float fast_tanh(float x) {
  return 1.0f - 2.0f / (__expf(2.0f * x) + 1.0f);
}
template<int CTRL>
__device__ __forceinline__ float bcast_quad(float v) {
  int r = __builtin_amdgcn_mov_dpp(__builtin_bit_cast(int, v), CTRL, 0xF, 0xF, true);
  return __builtin_bit_cast(float, r);
}

// ---- coherent (L1/L2-bypassing) access helpers: data moves via memory-side
// ---- Infinity Cache, which is shared by all XCDs -> no buffer_inv/wbl2 needed.
__device__ __forceinline__ void load16_bypass(short8& d, const ushort_t* p) {
  asm volatile("global_load_dwordx4 %0, %1, off sc0 sc1"
               : "=v"(d) : "v"(p) : "memory");
}
__device__ __forceinline__ void store_short_bypass(ushort_t* p, uint32 v) {
  asm volatile("global_store_short %0, %1, off sc0 sc1"
               :: "v"(p), "v"(v) : "memory");
}
__device__ __forceinline__ void store_dword_bypass(uint32* p, uint32 v) {
  asm volatile("global_store_dword %0, %1, off sc0 sc1"
               :: "v"(p), "v"(v) : "memory");
}
__device__ __forceinline__ uint32 load_dword_bypass(const uint32* p) {
  uint32 v;
  asm volatile("global_load_dword %0, %1, off sc0 sc1\n\ts_waitcnt vmcnt(0)"
               : "=v"(v) : "v"(p) : "memory");
  return v;
}
__device__ __forceinline__ void drain_vm() {
  asm volatile("s_waitcnt vmcnt(0)" ::: "memory");
}

// ---------------------------------------------------------------------------
// Pack kernel: BM[k][p] bf16 (k<256 -> W rows, k>=256 -> U rows), bias bp[p],
// xbf = x as bf16 in fragment-linear layout keyed (t, wave, q, lane, e):
//   offset = ((t*4 + w)*4 + q)*512 + lane*8 + e
//   row = w*16 + (lane&15); k = q*32 + (lane>>4)*8 + e; src x[row][t][k]
// Also zero h double-buffer and flags.
// ---------------------------------------------------------------------------
__global__ void pack_init(const float* __restrict__ x,
                          const float* __restrict__ Wf, const float* __restrict__ Wi,
                          const float* __restrict__ Wo, const float* __restrict__ Wc,
                          const float* __restrict__ Uf, const float* __restrict__ Ui,
                          const float* __restrict__ Uo, const float* __restrict__ Uc,
                          const float* __restrict__ bf_, const float* __restrict__ bi_,
                          const float* __restrict__ bo_, const float* __restrict__ bc_,
                          ushort_t* __restrict__ BM, float* __restrict__ bp,
                          ushort_t* __restrict__ xbf,
                          ushort_t* __restrict__ hbuf, uint32* __restrict__ flags) {
  int idx = blockIdx.x * 256 + threadIdx.x;   // [0, SEQ*BATCH*INDIM)
  {
    int e = idx & 7, lane = (idx >> 3) & 63, q = (idx >> 9) & 3,
        w = (idx >> 11) & 3, t = idx >> 13;
    if (t < SEQ) {
      int row = w * 16 + (lane & 15);
      int k = q * 32 + (lane >> 4) * 8 + e;
      xbf[idx] = f2bf(x[(row * SEQ + t) * INDIM + k]);
    }
  }
  if (idx < KTOT * NP) {
    int k = idx >> 10;
    int p = idx & (NP - 1);
    int g = p & 3, n = p >> 2;
    const float* W4[4] = {Wf, Wi, Wo, Wc};
    const float* U4[4] = {Uf, Ui, Uo, Uc};
    float v = (k < HID) ? W4[g][k * HID + n] : U4[g][(k - HID) * HID + n];
    BM[idx] = f2bf(v);
  }
  if (idx < NP) {
    int g = idx & 3, n = idx >> 2;
    const float* B4[4] = {bf_, bi_, bo_, bc_};
    bp[idx] = B4[g][n];
  }
  if (idx < 2 * BATCH * HID) hbuf[idx] = 0;
  if (idx < NWG) flags[idx] = 0;
}

// ---------------------------------------------------------------------------
// Persistent recurrence kernel. 64 WGs x 256 thr. No cache-wide fences:
// h + flags exchanged via sc0/sc1 bypass ops through the coherent L3.
// Pipeline per step: x-MFMAs (independent of h) issue BEFORE the flag poll.
// ---------------------------------------------------------------------------
__global__ __launch_bounds__(256, 1) void lstm_seq(
    const ushort_t* __restrict__ xbf, const ushort_t* __restrict__ BM,
    const float* __restrict__ bp, ushort_t* hbuf, uint32* flags,
    float* __restrict__ out)
{
  const int j    = blockIdx.x;
  const int tid  = threadIdx.x;
  const int wave = tid >> 6;
  const int lane = tid & 63;
  const int lhi  = lane >> 4;    // 0..3
  const int llo  = lane & 15;    // 0..15

  // persistent B fragments (384x16 slice in VGPRs for the whole sequence)
  short8 bfrag[12];
#pragma unroll
  for (int kf = 0; kf < 12; ++kf) {
#pragma unroll
    for (int e = 0; e < 8; ++e) {
      int k = kf * 32 + lhi * 8 + e;
      bfrag[kf][e] = (short)BM[k * NP + j * NCOL + llo];
    }
  }
  const float bias = bp[j * NCOL + llo];

  float c_reg[4] = {0.f, 0.f, 0.f, 0.f};
  const int arow  = wave * 16 + llo;        // batch row this lane LOADS (A layout)
  const int crow0 = wave * 16 + lhi * 4;    // batch row base this lane OWNS (C layout)
  const int nglob = j * 4 + (llo >> 2);     // global hidden col
  const int g     = lane & 3;               // gate id of this lane's column

  ushort_t* hb0 = hbuf;
  ushort_t* hb1 = hbuf + BATCH * HID;

  // preload x fragments for t=0 (fragment-linear, fully coalesced, cached)
  const ushort_t* xw = xbf + wave * 2048 + lane * 8;
  short8 xq[4];
#pragma unroll
  for (int q = 0; q < 4; ++q) xq[q] = *(const short8*)(xw + q * 512);

  for (int t = 0; t < SEQ; ++t) {
    // --- x part first: independent of h, hides behind barrier latency ---
    float4_t acc = {bias, bias, bias, bias};
#pragma unroll
    for (int q = 0; q < 4; ++q)
      acc = __builtin_amdgcn_mfma_f32_16x16x32_bf16(xq[q], bfrag[8 + q], acc, 0, 0, 0);

    // --- wait for all WGs to have finished step t-1 ---
    if (t > 0) {
      if (tid < NWG) {
        while (load_dword_bypass(&flags[tid]) < (uint32)t) { }
      }
      __syncthreads();
    }

    // --- h fragments: bypass loads (stale-L2-proof; served from L3) ---
    const ushort_t* hbr = (t & 1) ? hb1 : hb0;
    ushort_t*       hbw = (t & 1) ? hb0 : hb1;
    const ushort_t* hrow = hbr + arow * HID + lhi * 8;
    short8 hf[8];
#pragma unroll
    for (int kf = 0; kf < 8; ++kf) load16_bypass(hf[kf], hrow + kf * 32);
    asm volatile("s_waitcnt vmcnt(0)"
                 : "+v"(hf[0]), "+v"(hf[1]), "+v"(hf[2]), "+v"(hf[3]),
                   "+v"(hf[4]), "+v"(hf[5]), "+v"(hf[6]), "+v"(hf[7])
                 :: "memory");

#pragma unroll
    for (int kf = 0; kf < 8; ++kf)
      acc = __builtin_amdgcn_mfma_f32_16x16x32_bf16(hf[kf], bfrag[kf], acc, 0, 0, 0);

    // --- gates + state update (all four activations sigmoid, per ref) ---
#pragma unroll
    for (int r = 0; r < 4; ++r) {
      float s  = fast_sigmoid(acc[r]);
      float fv = bcast_quad<0x00>(s);
      float iv = bcast_quad<0x55>(s);
      float ov = bcast_quad<0xAA>(s);
      float cv = bcast_quad<0xFF>(s);
      float cn = fv * c_reg[r] + iv * cv;
      c_reg[r] = cn;
      float hv = ov * fast_tanh(cn);
      if (g == 0) {
        int row = crow0 + r;
        store_short_bypass(hbw + row * HID + nglob, (uint32)f2bf(hv));
        out[(row * SEQ + t) * HID + nglob] = hv;             // cached store
        if (t == SEQ - 1) {
          out[HSZ + row * HID + nglob] = hv;                 // h_T
          out[HSZ + BATCH * HID + row * HID + nglob] = cn;   // c_T
        }
      }
    }

    // --- signal: drain own stores, WG barrier, publish step count ---
    if (t < SEQ - 1) {
      drain_vm();          // per-thread: h write-through retired => in L3
      __syncthreads();
      if (tid == 0) store_dword_bypass(&flags[j], (uint32)(t + 1));
      // prefetch x for t+1 (issued behind the signal; consumed pre-poll)
      const ushort_t* xn = xbf + (t + 1) * 8192 + wave * 2048 + lane * 8;
#pragma unroll
      for (int q = 0; q < 4; ++q) xq[q] = *(const short8*)(xn + q * 512);
    }
  }
}

// ---------------------------------------------------------------------------
// Workspace layout (bytes):
//   [0, 786432)          BM    bf16 384x1024
//   [786432, 790528)     bp    fp32 1024
//   [790528, 856064)     hbuf  bf16 2 x 64 x 256 (double buffer)
//   [856064, 856320)     flags uint32 x 64
//   [1048576, 34603008)  xbf   bf16 fragment-linear x (33.5 MB)
// Total ~34.6 MB.
// ---------------------------------------------------------------------------
extern "C" void kernel_launch(void* const* d_in, const int* in_sizes, int n_in,
                              void* d_out, int out_size, void* d_ws, size_t ws_size,
                              hipStream_t stream) {
  const float* xp  = (const float*)d_in[0];
  const float* Uf  = (const float*)d_in[1];
  const float* Wf  = (const float*)d_in[2];
  const float* bf_ = (const float*)d_in[3];
  const float* Ui  = (const float*)d_in[4];
  const float* Wi  = (const float*)d_in[5];
  const float* bi_ = (const float*)d_in[6];
  const float* Uo  = (const float*)d_in[7];
  const float* Wo  = (const float*)d_in[8];
  const float* bo_ = (const float*)d_in[9];
  const float* Uc  = (const float*)d_in[10];
  const float* Wc  = (const float*)d_in[11];
  const float* bc_ = (const float*)d_in[12];

  char* ws = (char*)d_ws;
  ushort_t* BM    = (ushort_t*)(ws);
  float*    bp    = (float*)(ws + 786432);
  ushort_t* hbuf  = (ushort_t*)(ws + 790528);
  uint32*   flags = (uint32*)(ws + 856064);
  ushort_t* xbf   = (ushort_t*)(ws + 1048576);
  float*    out   = (float*)d_out;

  // 65536 blocks x 256 = exactly SEQ*BATCH*INDIM threads (one per x element)
  pack_init<<<65536, 256, 0, stream>>>(xp, Wf, Wi, Wo, Wc, Uf, Ui, Uo, Uc,
                                       bf_, bi_, bo_, bc_, BM, bp, xbf, hbuf, flags);
  lstm_seq<<<NWG, 256, 0, stream>>>(xbf, BM, bp, hbuf, flags, out);
}